// Round 19
// baseline (2460.944 us; speedup 1.0000x reference)
//
#include <hip/hip_runtime.h>
#include <cmath>

typedef unsigned long long u64;
typedef __attribute__((ext_vector_type(8))) short short8;
typedef __attribute__((ext_vector_type(4))) float f32x4;
typedef __attribute__((ext_vector_type(4))) double f64x4;

#define N_ANCH   147456      // 128*128*9
#define N_SCREEN 3600        // screen candidates (rank margin 600)
#define N_PRE    3000
#define N_POST   300
#define NWORDS   47          // ceil(3000/64)
#define SEL_CAP  4096

__device__ inline short f2bf(float f) {          // f32 -> bf16 RNE
    unsigned u = __float_as_uint(f);
    unsigned r = u + 0x7FFFu + ((u >> 16) & 1u);
    return (short)(r >> 16);
}

// ---------------- prep: x -> xT[h][w][c] bf16 ----------------
__global__ __launch_bounds__(256) void rpn_prep_xT(const float* __restrict__ x,
                                                   short* __restrict__ xT) {
    __shared__ short tile[32][258];
    const int h  = blockIdx.x;
    const int w0 = blockIdx.y * 32;
    const int c0 = blockIdx.z * 256;
    const int tid = threadIdx.x;
    const int wi = tid & 31, cs = tid >> 5;
    #pragma unroll
    for (int it = 0; it < 32; ++it) {
        int c = it * 8 + cs;
        float v = x[(size_t)(c0 + c) * 16384 + h * 128 + w0 + wi];
        tile[wi][c] = f2bf(v);
    }
    __syncthreads();
    #pragma unroll
    for (int it = 0; it < 32; ++it) {
        int i = tid + it * 256;
        int wj = i >> 8, c = i & 255;
        xT[((size_t)h * 128 + w0 + wj) * 1024 + c0 + c] = tile[wj][c];
    }
}

// ---------------- prep: wb -> wT[t][oc][c] bf16 ----------------
__global__ __launch_bounds__(256) void rpn_prep_wbf(const float* __restrict__ wb,
                                                    short* __restrict__ wT) {
    __shared__ float wtile[2304];
    const int oc = blockIdx.x;
    const int c0 = blockIdx.y * 256;
    const int tid = threadIdx.x;
    #pragma unroll
    for (int it = 0; it < 9; ++it) {
        int i = tid + it * 256;
        wtile[i] = wb[(size_t)oc * 9216 + c0 * 9 + i];
    }
    __syncthreads();
    #pragma unroll
    for (int it = 0; it < 9; ++it) {
        int i = tid + it * 256;
        int t = i >> 8, c = i & 255;
        wT[((size_t)t * 512 + oc) * 1024 + c0 + c] = f2bf(wtile[c * 9 + t]);
    }
}

// ---------------- prep: wb -> wt[c*9+t][oc] f32 (for f64 rescue; runs AFTER screen) ----
__global__ __launch_bounds__(256) void rpn_prep_w(const float* __restrict__ wb,
                                                  float* __restrict__ wt) {
    __shared__ float tile[64][65];
    const int bx = blockIdx.x;           // rem tile: 144 * 64 = 9216
    const int by = blockIdx.y;           // oc  tile:   8 * 64 = 512
    const int tid = threadIdx.x;
    #pragma unroll
    for (int it = 0; it < 16; ++it) {
        int i = tid + it * 256;
        int r = i >> 6, c = i & 63;
        tile[r][c] = wb[(size_t)(by * 64 + r) * 9216 + bx * 64 + c];
    }
    __syncthreads();
    #pragma unroll
    for (int it = 0; it < 16; ++it) {
        int i = tid + it * 256;
        int r = i >> 6, c = i & 63;
        wt[(size_t)(bx * 64 + r) * 512 + by * 64 + c] = tile[c][r];
    }
}

__global__ void rpn_prep_wht(const float* __restrict__ wc, const float* __restrict__ wr,
                             float* __restrict__ wht) {
    int i = blockIdx.x * 256 + threadIdx.x;           // < 512*56
    if (i >= 512 * 56) return;
    int c = i / 56, k = i - c * 56;
    float v = 0.f;
    if (k < 18)       v = wc[k * 512 + c];
    else if (k < 54)  v = wr[(k - 18) * 512 + c];
    wht[i] = v;
}

// ---------------- bf16 MFMA SCREEN v3: 512 thr, 128 oc/block, depth-2 prefetch --------
// Block 512 thr = 8 waves. Wave: 32 oc x 64 px (wocB=(wave&3)*32, wpx=(wave>>2)*64).
// Grid (128 rows, 4 ocT of 128 oc) -> x halo read 4x instead of 8x.
// K-chunks of 32 channels; ping-pong register buffers give 2-chunk prefetch depth.
#define STAGE_LOADM(WREG, XREG, CN)                                            \
    {                                                                          \
        _Pragma("unroll")                                                      \
        for (int it = 0; it < 9; ++it)                                         \
            WREG[it] = *(const short8*)&wT[wgo[it] + (CN)];                    \
        _Pragma("unroll")                                                      \
        for (int it = 0; it < 4; ++it)                                         \
            XREG[it] = (xgo[it] >= 0) ? *(const short8*)&xT[xgo[it] + (CN)]    \
                                      : zer;                                   \
    }
#define STAGE_WRITEM(WREG, XREG)                                               \
    {                                                                          \
        _Pragma("unroll")                                                      \
        for (int it = 0; it < 9; ++it) *(short8*)&wsm[wlo[it]] = WREG[it];     \
        _Pragma("unroll")                                                      \
        for (int it = 0; it < 4; ++it)                                         \
            if (xlo[it] >= 0) *(short8*)&xsm[xlo[it]] = XREG[it];              \
    }
#define MFMA_CHUNKM()                                                          \
    {                                                                          \
        _Pragma("unroll")                                                      \
        for (int t = 0; t < 9; ++t) {                                          \
            int kh = t / 3, kw = t - kh * 3;                                   \
            int ra0 = t * 128 + wocB + l15;                                    \
            int ra1 = ra0 + 16;                                                \
            short8 a0 = *(const short8*)&wsm[ra0 * 32 + ((lg ^ ((ra0 >> 1) & 3)) << 3)]; \
            short8 a1 = *(const short8*)&wsm[ra1 * 32 + ((lg ^ ((ra1 >> 1) & 3)) << 3)]; \
            _Pragma("unroll")                                                  \
            for (int nf = 0; nf < 4; ++nf) {                                   \
                int rb = kh * 130 + wpx + nf * 16 + l15 + kw;                  \
                short8 b = *(const short8*)&xsm[rb * 32 + ((lg ^ ((rb >> 1) & 3)) << 3)]; \
                acc[0][nf] = __builtin_amdgcn_mfma_f32_16x16x32_bf16(a0, b, acc[0][nf], 0, 0, 0); \
                acc[1][nf] = __builtin_amdgcn_mfma_f32_16x16x32_bf16(a1, b, acc[1][nf], 0, 0, 0); \
            }                                                                  \
        }                                                                      \
    }

__global__ __launch_bounds__(512, 2) void rpn_screen_mfma(
    const short* __restrict__ xT, const short* __restrict__ wT,
    const float* __restrict__ bb, const float* __restrict__ wht_,
    float* __restrict__ logits) {
    const int row = blockIdx.x;
    const int ocB = blockIdx.y * 128;
    const int tid = threadIdx.x;
    const int wave = tid >> 6, lane = tid & 63;
    const int l15 = lane & 15, lg = lane >> 4;
    const int wocB = (wave & 3) * 32;
    const int wpx  = (wave >> 2) * 64;
    __shared__ __attribute__((aligned(16))) short wsm[1152 * 32];  // 73,728B
    __shared__ __attribute__((aligned(16))) short xsm[390 * 32];   // 24,960B

    // ---- hoisted staging geometry (chunk-invariant; add c0 per chunk) ----
    size_t wgo[9];  int wlo[9];
    #pragma unroll
    for (int it = 0; it < 9; ++it) {
        int i = tid + it * 512;          // 0..4607
        int r = i >> 2, s = i & 3;       // r < 1152
        int t = r >> 7, ocl = r & 127;
        wgo[it] = ((size_t)t * 512 + ocB + ocl) * 1024 + s * 8;
        wlo[it] = r * 32 + ((s ^ ((r >> 1) & 3)) << 3);
    }
    long xgo[4]; int xlo[4];
    #pragma unroll
    for (int it = 0; it < 4; ++it) {
        int i = tid + it * 512;
        xlo[it] = -1; xgo[it] = -1;
        if (i < 1560) {
            int r = i >> 2, s = i & 3;
            int r3 = r / 130, col = r - r3 * 130;
            int h = row - 1 + r3, wc = col - 1;
            xlo[it] = r * 32 + ((s ^ ((r >> 1) & 3)) << 3);
            xgo[it] = (h >= 0 && h < 128 && wc >= 0 && wc < 128)
                      ? (long)(((size_t)h * 128 + wc) * 1024 + s * 8) : -1;
        }
    }

    f32x4 acc[2][4];
    #pragma unroll
    for (int mi = 0; mi < 2; ++mi)
        #pragma unroll
        for (int nf = 0; nf < 4; ++nf)
            acc[mi][nf] = (f32x4){0.f, 0.f, 0.f, 0.f};

    short8 wregA[9], xregA[4], wregB[9], xregB[4];
    const short8 zer = {0, 0, 0, 0, 0, 0, 0, 0};

    STAGE_LOADM(wregA, xregA, 0);
    STAGE_LOADM(wregB, xregB, 32);

    for (int i2 = 0; i2 < 16; ++i2) {
        int cA = i2 * 64;
        __syncthreads();
        STAGE_WRITEM(wregA, xregA);
        __syncthreads();
        if (cA + 64 < 1024) STAGE_LOADM(wregA, xregA, cA + 64);
        MFMA_CHUNKM();
        __syncthreads();
        STAGE_WRITEM(wregB, xregB);
        __syncthreads();
        if (cA + 96 < 1024) STAGE_LOADM(wregB, xregB, cA + 96);
        MFMA_CHUNKM();
    }

    // epilogue: bias+relu (C/D map: oc = row = lg*4+reg, px = col = l15)
    float r_[8][4];
    #pragma unroll
    for (int mi = 0; mi < 2; ++mi)
        #pragma unroll
        for (int rr = 0; rr < 4; ++rr) {
            int ocg = ocB + wocB + mi * 16 + lg * 4 + rr;
            float bv = bb[ocg];
            #pragma unroll
            for (int nf = 0; nf < 4; ++nf)
                r_[mi * 4 + rr][nf] = fmaxf(acc[mi][nf][rr] + bv, 0.f);
        }
    int pxg[4];
    #pragma unroll
    for (int nf = 0; nf < 4; ++nf) pxg[nf] = row * 128 + wpx + nf * 16 + l15;
    for (int qc = 0; qc < 14; ++qc) {
        float wq[8][4];
        #pragma unroll
        for (int p = 0; p < 8; ++p) {
            int ocg = ocB + wocB + (p >> 2) * 16 + lg * 4 + (p & 3);
            float4 wv = *(const float4*)&wht_[(size_t)ocg * 56 + qc * 4];
            wq[p][0] = wv.x; wq[p][1] = wv.y; wq[p][2] = wv.z; wq[p][3] = wv.w;
        }
        #pragma unroll
        for (int nf = 0; nf < 4; ++nf) {
            #pragma unroll
            for (int qq = 0; qq < 4; ++qq) {
                float s = 0.f;
                #pragma unroll
                for (int p = 0; p < 8; ++p) s = fmaf(r_[p][nf], wq[p][qq], s);
                s += __shfl_xor(s, 16);
                s += __shfl_xor(s, 32);          // sum over wave's 32 oc
                if (lg == 0)
                    atomicAdd(&logits[(size_t)pxg[nf] * 56 + qc * 4 + qq], s);
            }
        }
    }
}

// ---------------- f32 screen decode + hist1 (fused) ----------------
__global__ void rpn_screen_decode(
    const float* __restrict__ logits, const float* __restrict__ bc,
    const float* __restrict__ br, unsigned* __restrict__ keys32,
    unsigned* __restrict__ hist1) {
    int aidx = blockIdx.x * 256 + threadIdx.x;
    if (aidx >= N_ANCH) return;
    int px = aidx / 9, a = aidx - px * 9;
    int wix = px & 127, hix = px >> 7;
    float Xf = (float)(wix * 16), Yf = (float)(hix * 16);
    int ri = a / 3, si = a - ri * 3;
    double rr  = (ri == 0) ? 0.5 : ((ri == 1) ? 1.0 : 2.0);
    double scl = (si == 0) ? 8.0 : ((si == 1) ? 16.0 : 32.0);
    double wA = 16.0 * scl * sqrt(1.0 / rr);
    double hA = 16.0 * scl * sqrt(rr);
    float c0 = (float)(-0.5 * wA), c1 = (float)(-0.5 * hA);
    float c2 = (float)( 0.5 * wA), c3 = (float)( 0.5 * hA);
    float ax1 = Xf + c0, ay1 = Yf + c1, ax2 = Xf + c2, ay2 = Yf + c3;
    float aw = ax2 - ax1, ah = ay2 - ay1;
    float acx = ax1 + 0.5f * aw, acy = ay1 + 0.5f * ah;
    const float* L = &logits[(size_t)px * 56];
    float l0 = L[2 * a]     + bc[2 * a];
    float l1 = L[2 * a + 1] + bc[2 * a + 1];
    float dx = L[18 + 4 * a + 0] + br[4 * a + 0];
    float dy = L[18 + 4 * a + 1] + br[4 * a + 1];
    float dw = L[18 + 4 * a + 2] + br[4 * a + 2];
    float dh = L[18 + 4 * a + 3] + br[4 * a + 3];
    float cx = dx * aw + acx, cy = dy * ah + acy;
    float bw = expf(dw) * aw, bh = expf(dh) * ah;
    float x1 = fminf(fmaxf(cx - 0.5f * bw, 0.f), 2048.f);
    float y1 = fminf(fmaxf(cy - 0.5f * bh, 0.f), 2048.f);
    float x2 = fminf(fmaxf(cx + 0.5f * bw, 0.f), 2048.f);
    float y2 = fminf(fmaxf(cy + 0.5f * bh, 0.f), 2048.f);
    // fuzzy validity: wide slack for bf16 screen error; exact test in f64 rescue
    bool valid = (x2 - x1 >= 12.0f) && (y2 - y1 >= 12.0f);
    float m = fmaxf(l0, l1);
    float e0 = expf(l0 - m), e1 = expf(l1 - m);
    float fg = e1 / (e0 + e1);
    float msk = valid ? fg : -INFINITY;
    unsigned kb = __float_as_uint(msk);
    kb = (kb & 0x80000000u) ? ~kb : (kb | 0x80000000u);
    keys32[aidx] = kb;
    atomicAdd(&hist1[kb >> 16], 1u);
}

// ---------------- top-N_SCREEN: two-level radix select on fp32 key ----------------
__global__ void rpn_select1(const unsigned* __restrict__ hist, unsigned* __restrict__ meta) {
    __shared__ unsigned seg[256];
    __shared__ unsigned suf[257];
    int t = threadIdx.x;
    unsigned s = 0;
    for (int j = 0; j < 256; ++j) s += hist[t * 256 + j];
    seg[t] = s;
    __syncthreads();
    if (t == 0) {
        unsigned run = 0; suf[256] = 0;
        for (int q = 255; q >= 0; --q) { run += seg[q]; suf[q] = run; }
    }
    __syncthreads();
    if (suf[t + 1] < N_SCREEN && suf[t] >= N_SCREEN) {
        unsigned cum = suf[t + 1];
        for (int b = t * 256 + 255; b >= t * 256; --b) {
            unsigned prev = cum;
            cum += hist[b];
            if (cum >= N_SCREEN) { meta[0] = (unsigned)b; meta[1] = prev; break; }
        }
    }
}

__global__ void rpn_hist2(const unsigned* __restrict__ keys, const unsigned* __restrict__ meta,
                          unsigned* __restrict__ hist2) {
    int i = blockIdx.x * 256 + threadIdx.x;
    if (i >= N_ANCH) return;
    unsigned B = meta[0];
    unsigned k = keys[i];
    if ((k >> 16) == B) atomicAdd(&hist2[k & 0xFFFFu], 1u);
}

__global__ void rpn_select2(const unsigned* __restrict__ hist2, unsigned* __restrict__ meta) {
    __shared__ unsigned seg[256];
    __shared__ unsigned suf[257];
    int t = threadIdx.x;
    unsigned s = 0;
    for (int j = 0; j < 256; ++j) s += hist2[t * 256 + j];
    seg[t] = s;
    __syncthreads();
    if (t == 0) {
        unsigned run = 0; suf[256] = 0;
        for (int q = 255; q >= 0; --q) { run += seg[q]; suf[q] = run; }
    }
    __syncthreads();
    unsigned need = N_SCREEN - meta[1];          // >= 1 by construction
    if (suf[t + 1] < need && suf[t] >= need) {
        unsigned cum = suf[t + 1];
        for (int b = t * 256 + 255; b >= t * 256; --b) {
            cum += hist2[b];
            if (cum >= need) { meta[3] = (meta[0] << 16) | (unsigned)b; break; }
        }
    }
}

// compact + pixel-mark fused
__global__ void rpn_compact(const unsigned* __restrict__ keys, unsigned* meta,
                            int* __restrict__ sel_idx, unsigned* __restrict__ pxflag) {
    int i = blockIdx.x * 256 + threadIdx.x;
    if (i >= N_ANCH) return;
    if (keys[i] >= meta[3]) {
        unsigned pos = atomicAdd(&meta[4], 1u);
        if (pos < SEL_CAP) {
            sel_idx[pos] = i;
            pxflag[i / 9] = 1u;
        }
    }
}

__global__ void rpn_px_compact(const unsigned* __restrict__ pxflag, unsigned* meta,
                               int* __restrict__ pxlist, int* __restrict__ pxslot) {
    int px = blockIdx.x * 256 + threadIdx.x;
    if (px >= 16384) return;
    if (pxflag[px]) {
        int slot = (int)atomicAdd(&meta[5], 1u);
        pxlist[slot] = px;
        pxslot[px] = slot;
    }
}

// ---------------- f64 rescue GEMM v7b: f64 MFMA with SELF-CALIBRATING D layout ----------
// Grid (256 slot-tiles of 16, 8 ocT of 64). Block: 256 thr = 4 waves, wave = 16-oc group.
// Full K=9216 in-block -> direct stores, no atomics. K order: k = c*9 + tap (c asc).
__global__ __launch_bounds__(256) void rpn_rescue_gemm(
    const float* __restrict__ x, const float* __restrict__ wt,
    const int* __restrict__ pxlist, const unsigned* __restrict__ meta,
    double* __restrict__ base64) {
    int npx = (int)meta[5];
    int s0 = blockIdx.x * 16;
    if (s0 >= npx) return;
    const int tid  = threadIdx.x;
    const int wave = tid >> 6, lane = tid & 63;
    const int l15 = lane & 15, lg = lane >> 4;
    const int ocg = blockIdx.y * 64 + wave * 16;     // wave's 16-oc group base
    __shared__ double xs[144][17];                   // [kk][slot], 19,584 B

    // ---- layout probes ----
    f64x4 p1 = (f64x4){0.0, 0.0, 0.0, 0.0};
    f64x4 p2 = (f64x4){0.0, 0.0, 0.0, 0.0};
    p1 = __builtin_amdgcn_mfma_f64_16x16x4f64((double)l15, 1.0, p1, 0, 0, 0);
    p2 = __builtin_amdgcn_mfma_f64_16x16x4f64(1.0, (double)l15, p2, 0, 0, 0);
    int srow[4], scol[4];
    #pragma unroll
    for (int r = 0; r < 4; ++r) {
        srow[r] = (int)(p1[r] * 0.25 + 0.5);     // intended slot feeding this output
        scol[r] = (int)(p2[r] * 0.25 + 0.5);     // intended oc-offset feeding this output
    }

    // hoisted gather geometry: task j = tid + it*256 (exactly 2304 = 144*16 tasks)
    int sp_off[9];      // yy*128+xx or -1 (OOB)
    int ch_of[9];       // cLocal (0..15)
    #pragma unroll
    for (int it = 0; it < 9; ++it) {
        int j = tid + it * 256;
        int kk = j >> 4, slot = j & 15;
        int cl = kk / 9, tap = kk - cl * 9;
        int sg = s0 + slot;
        int pv = pxlist[(sg < npx) ? sg : s0];
        int yy = (pv >> 7) + tap / 3 - 1;
        int xx = (pv & 127) + tap % 3 - 1;
        sp_off[it] = (yy >= 0 && yy < 128 && xx >= 0 && xx < 128) ? (yy * 128 + xx) : -1;
        ch_of[it] = cl;
    }

    f64x4 acc = (f64x4){0.0, 0.0, 0.0, 0.0};
    float xreg[9];

    // prologue: gather channels 0..15
    #pragma unroll
    for (int it = 0; it < 9; ++it)
        xreg[it] = (sp_off[it] >= 0) ? x[(size_t)ch_of[it] * 16384 + sp_off[it]] : 0.f;

    const size_t wlane = (size_t)(ocg + l15) + (size_t)lg * 512;
    for (int c0 = 0; c0 < 1024; c0 += 16) {
        __syncthreads();
        #pragma unroll
        for (int it = 0; it < 9; ++it) {
            int j = tid + it * 256;
            xs[j >> 4][j & 15] = (double)xreg[it];
        }
        __syncthreads();
        if (c0 + 16 < 1024) {
            #pragma unroll
            for (int it = 0; it < 9; ++it)
                xreg[it] = (sp_off[it] >= 0)
                           ? x[(size_t)(c0 + 16 + ch_of[it]) * 16384 + sp_off[it]] : 0.f;
        }
        // 36 k-steps of K=4 over this round's 144 (c,tap) values.
        const size_t wbase = (size_t)c0 * 4608 + wlane;
        #pragma unroll
        for (int ks = 0; ks < 36; ++ks) {
            double a = xs[ks * 4 + lg][l15];
            double b = (double)wt[wbase + (size_t)ks * 2048];
            acc = __builtin_amdgcn_mfma_f64_16x16x4f64(a, b, acc, 0, 0, 0);
        }
    }
    #pragma unroll
    for (int r = 0; r < 4; ++r) {
        int slot = s0 + srow[r];
        if (slot < npx)
            base64[(size_t)slot * 512 + ocg + scol[r]] = acc[r];
    }
}

// ---------------- f64 rescue heads: LDS-staged base, bias+relu at staging ----------------
__global__ __launch_bounds__(256) void rpn_rescue_heads(
    const double* __restrict__ base64, const float* __restrict__ wht,
    const float* __restrict__ bb, const float* __restrict__ bc,
    const float* __restrict__ br, const unsigned* __restrict__ meta,
    double* __restrict__ logits64) {
    int npx = (int)meta[5]; if (npx > SEL_CAP) npx = SEL_CAP;
    int slot0 = blockIdx.x * 4;
    if (slot0 >= npx) return;
    const int tid = threadIdx.x;
    __shared__ double bs[4][514];        // padded: rows 4 banks apart
    for (int i = tid; i < 4 * 512; i += 256) {
        int s = i >> 9, c = i & 511;
        int slt = slot0 + s;
        double v = (slt < npx) ? base64[(size_t)slt * 512 + c] : 0.0;
        double r = v + (double)bb[c];
        bs[s][c] = (r > 0.0) ? r : 0.0;  // conv bias + relu applied once here
    }
    __syncthreads();
    if (tid < 224) {
        int s = tid / 56, q = tid - s * 56;
        int slt = slot0 + s;
        if (slt < npx) {
            double acc = (q < 18) ? (double)bc[q] : ((q < 54) ? (double)br[q - 18] : 0.0);
            const double* b = bs[s];
            #pragma unroll 8
            for (int c = 0; c < 512; ++c)
                acc = fma(b[c], (double)wht[c * 56 + q], acc);
            logits64[(size_t)slt * 56 + q] = acc;
        }
    }
}

// ---------------- f64 rescue decode: exact boxes/scores/keys ----------------
__global__ void rpn_rescue_decode(
    const double* __restrict__ logits64, const int* __restrict__ sel_idx,
    const int* __restrict__ pxslot, const unsigned* __restrict__ meta,
    double* __restrict__ boxes_d, float* __restrict__ sc32, u64* __restrict__ sel) {
    int i = blockIdx.x * 256 + threadIdx.x;
    unsigned M = meta[4]; if (M > SEL_CAP) M = SEL_CAP;
    if (i >= (int)M) return;
    int aidx = sel_idx[i];
    int px = aidx / 9, a = aidx - px * 9;
    int slot = pxslot[px];
    int wix = px & 127, hix = px >> 7;
    float Xf = (float)(wix * 16), Yf = (float)(hix * 16);
    int ri = a / 3, si = a - ri * 3;
    double rr  = (ri == 0) ? 0.5 : ((ri == 1) ? 1.0 : 2.0);
    double scl = (si == 0) ? 8.0 : ((si == 1) ? 16.0 : 32.0);
    double wA = 16.0 * scl * sqrt(1.0 / rr);
    double hA = 16.0 * scl * sqrt(rr);
    // anchors are float32 in the reference (np.asarray(ba, np.float32))
    float c0 = (float)(-0.5 * wA), c1 = (float)(-0.5 * hA);
    float c2 = (float)( 0.5 * wA), c3 = (float)( 0.5 * hA);
    float ax1 = Xf + c0, ay1 = Yf + c1, ax2 = Xf + c2, ay2 = Yf + c3;
    float awf = ax2 - ax1, ahf = ay2 - ay1;
    float acxf = ax1 + 0.5f * awf, acyf = ay1 + 0.5f * ahf;
    double aw = (double)awf, ah = (double)ahf;
    double acx = (double)acxf, acy = (double)acyf;
    const double* L = &logits64[(size_t)slot * 56];
    double l0 = L[2 * a], l1 = L[2 * a + 1];
    double dx = L[18 + 4 * a + 0], dy = L[18 + 4 * a + 1];
    double dw = L[18 + 4 * a + 2], dh = L[18 + 4 * a + 3];
    double cx = dx * aw + acx, cy = dy * ah + acy;
    double bw = exp(dw) * aw, bh = exp(dh) * ah;
    double x1 = fmin(fmax(cx - 0.5 * bw, 0.0), 2048.0);
    double y1 = fmin(fmax(cy - 0.5 * bh, 0.0), 2048.0);
    double x2 = fmin(fmax(cx + 0.5 * bw, 0.0), 2048.0);
    double y2 = fmin(fmax(cy + 0.5 * bh, 0.0), 2048.0);
    bool valid = (x2 - x1 >= 16.0) && (y2 - y1 >= 16.0);
    double m = fmax(l0, l1);
    double e0 = exp(l0 - m), e1 = exp(l1 - m);
    double fg = e1 / (e0 + e1);
    double msk = valid ? fg : -INFINITY;
    double* bd = &boxes_d[(size_t)aidx * 4];
    bd[0] = x1; bd[1] = y1; bd[2] = x2; bd[3] = y2;
    sc32[aidx] = (float)msk;
    long long ll = __double_as_longlong(msk);
    u64 u = (ll < 0) ? ~(u64)ll : ((u64)ll | 0x8000000000000000ull);
    sel[i] = (u & 0xFFFFFFFFFFFC0000ull) | (u64)(0x3FFFFu - (unsigned)aidx);
}

// ---------------- exact sort of candidates, take top-3000 ----------------
__global__ __launch_bounds__(1024) void rpn_sort(
    const u64* __restrict__ sel, const unsigned* __restrict__ meta,
    const double* __restrict__ boxes_d, const float* __restrict__ sc32,
    float* __restrict__ out, double* __restrict__ bsel, unsigned* __restrict__ vsel) {
    __shared__ u64 ss[SEL_CAP];
    int tid = threadIdx.x;
    int M = (int)meta[4]; if (M > SEL_CAP) M = SEL_CAP;
    for (int i = tid; i < SEL_CAP; i += 1024) ss[i] = (i < M) ? sel[i] : 0ULL;
    __syncthreads();
    for (int k = 2; k <= SEL_CAP; k <<= 1) {
        for (int j = k >> 1; j > 0; j >>= 1) {
            for (int i = tid; i < SEL_CAP; i += 1024) {
                int l = i ^ j;
                if (l > i) {
                    u64 a = ss[i], b = ss[l];
                    bool desc = (i & k) == 0;
                    if ((a < b) == desc) { ss[i] = b; ss[l] = a; }
                }
            }
            __syncthreads();
        }
    }
    for (int r = tid; r < N_PRE; r += 1024) {
        u64 key = ss[r];
        unsigned idx = 0x3FFFFu - (unsigned)(key & 0x3FFFFull);
        out[N_POST * 4 + r] = sc32[idx];
        const double* bd = &boxes_d[(size_t)idx * 4];
        double* dst = &bsel[(size_t)r * 4];
        dst[0] = bd[0]; dst[1] = bd[1]; dst[2] = bd[2]; dst[3] = bd[3];
        vsel[r] = (key >> 63) ? 1u : 0u;
    }
}

// ---------------- NMS (fp64 IoU) ----------------
__global__ void rpn_nms_mask(const double* __restrict__ bsel, u64* __restrict__ mask) {
    int t = blockIdx.x * 256 + threadIdx.x;
    if (t >= N_PRE * NWORDS) return;
    int i = t / NWORDS, w = t - i * NWORDS;
    const double* bi = &bsel[(size_t)i * 4];
    double bix1 = bi[0], biy1 = bi[1], bix2 = bi[2], biy2 = bi[3];
    double ai = (bix2 - bix1 + 1.0) * (biy2 - biy1 + 1.0);
    u64 bits = 0ULL;
    int j0 = w * 64;
    for (int jj = 0; jj < 64; ++jj) {
        int j = j0 + jj;
        if (j >= N_PRE || j == i) continue;
        const double* bj = &bsel[(size_t)j * 4];
        double aj = (bj[2] - bj[0] + 1.0) * (bj[3] - bj[1] + 1.0);
        double xx1 = fmax(bix1, bj[0]), yy1 = fmax(biy1, bj[1]);
        double xx2 = fmin(bix2, bj[2]), yy2 = fmin(biy2, bj[3]);
        double iw = fmax(xx2 - xx1 + 1.0, 0.0), ih = fmax(yy2 - yy1 + 1.0, 0.0);
        double inter = iw * ih;
        double iou = inter / (ai + aj - inter);
        if (iou > 0.5) bits |= 1ULL << jj;
    }
    mask[(size_t)i * NWORDS + w] = bits;
}

__global__ __launch_bounds__(64) void rpn_nms_scan(
    const u64* __restrict__ mask, const unsigned* __restrict__ vsel,
    unsigned* __restrict__ keep, unsigned* __restrict__ rank) {
    int lane = threadIdx.x;
    u64 remv = 0ULL;
    int kc = 0;
    u64 pre[8];
    unsigned vpre[8];
    #pragma unroll
    for (int q = 0; q < 8; ++q) {
        pre[q]  = (lane < NWORDS) ? mask[(size_t)q * NWORDS + lane] : 0ULL;
        vpre[q] = vsel[q];
    }
    for (int i0 = 0; i0 < N_PRE; i0 += 8) {
        u64 nxt[8];
        unsigned vnxt[8];
        #pragma unroll
        for (int q = 0; q < 8; ++q) {
            int r = i0 + 8 + q;
            nxt[q]  = (r < N_PRE && lane < NWORDS) ? mask[(size_t)r * NWORDS + lane] : 0ULL;
            vnxt[q] = (r < N_PRE) ? vsel[r] : 0u;
        }
        #pragma unroll
        for (int q = 0; q < 8; ++q) {
            int i = i0 + q;
            int word = i >> 6, bit = i & 63;
            u64 rw = __shfl(remv, word);
            bool sup = (rw >> bit) & 1ULL;
            bool kp = (vpre[q] != 0u) && !sup;
            if (kp) remv |= pre[q];
            if (lane == 0) { keep[i] = kp ? 1u : 0u; rank[i] = (unsigned)kc; }
            kc += kp ? 1 : 0;
        }
        #pragma unroll
        for (int q = 0; q < 8; ++q) { pre[q] = nxt[q]; vpre[q] = vnxt[q]; }
    }
}

__global__ void rpn_finalize(const unsigned* __restrict__ keep, const unsigned* __restrict__ rank,
                             const double* __restrict__ bsel, float* __restrict__ out) {
    int i = blockIdx.x * 256 + threadIdx.x;
    if (i < N_PRE && keep[i] && rank[i] < N_POST) {
        const double* b = &bsel[(size_t)i * 4];
        float4 v = make_float4((float)b[0], (float)b[1], (float)b[2], (float)b[3]);
        ((float4*)out)[rank[i]] = v;
    }
}

// ---------------- launch ----------------
extern "C" void kernel_launch(void* const* d_in, const int* in_sizes, int n_in,
                              void* d_out, int out_size, void* d_ws, size_t ws_size,
                              hipStream_t stream) {
    const float* x   = (const float*)d_in[0];
    const float* wb  = (const float*)d_in[1];
    const float* bb  = (const float*)d_in[2];
    const float* wc  = (const float*)d_in[3];
    const float* bc  = (const float*)d_in[4];
    const float* wr  = (const float*)d_in[5];
    const float* br  = (const float*)d_in[6];
    float* out = (float*)d_out;

    char* ws = (char*)d_ws;
    // Layout with overlays (total 56,490,752 B <= 57 MB proven-safe).
    // Phase 1 (prep+screen): xT@0 (33.5MB), wT@33.5MB (9.4MB) live.
    // Phase 2 (post-screen): wt@0 (18.9MB) and base64@18,874,368 (16.8MB)
    //   overlay the then-dead xT/wT regions.
    short*    xT       = (short*)(ws);                        // 33,554,432 (phase 1)
    float*    wt       = (float*)(ws);                        // 18,874,368 (phase 2)
    double*   base64   = (double*)(ws + 18874368);            // 16,777,216 (phase 2)
    short*    wT       = (short*)(ws + 33554432);             //  9,437,184 (phase 1)
    float*    logits32 = (float*)(ws + 42991616);             //  3,670,016
    float*    wht      = (float*)(ws + 46661632);             //    114,688
    double*   logits64 = (double*)(ws + 46776320);            //  1,835,008
    double*   boxes_d  = (double*)(ws + 48611328);            //  4,718,592
    float*    sc32     = (float*)(ws + 53329920);             //    589,824
    unsigned* keys32   = (unsigned*)(ws + 53919744);          //    589,824
    unsigned* hist1    = (unsigned*)(ws + 54509568);          //    262,144
    unsigned* hist2    = (unsigned*)(ws + 54771712);          //    262,144
    unsigned* meta     = (unsigned*)(ws + 55033856);          //        256
    int*      sel_idx  = (int*)(ws + 55034112);               //     16,384
    u64*      sel      = (u64*)(ws + 55050496);               //     32,768
    unsigned* pxflag   = (unsigned*)(ws + 55083264);          //     65,536
    int*      pxlist   = (int*)(ws + 55148800);               //     16,384
    int*      pxslot   = (int*)(ws + 55165184);               //     65,536
    double*   bsel     = (double*)(ws + 55230720);            //     96,000
    unsigned* vsel     = (unsigned*)(ws + 55326720);          //     12,032
    u64*      mask     = (u64*)(ws + 55338752);               //  1,128,000
    unsigned* keep     = (unsigned*)(ws + 56466752);          //     12,000
    unsigned* rank     = (unsigned*)(ws + 56478752);          //     12,000

    hipMemsetAsync(logits32, 0, 3670016, stream);
    hipMemsetAsync(hist1, 0, 262144 * 2 + 256, stream);       // hist1+hist2+meta
    hipMemsetAsync(pxflag, 0, 65536, stream);
    hipMemsetAsync(d_out, 0, N_POST * 4 * sizeof(float), stream);

    rpn_prep_xT      <<<dim3(128, 4, 4), 256, 0, stream>>>(x, xT);
    rpn_prep_wbf     <<<dim3(512, 4), 256, 0, stream>>>(wb, wT);
    rpn_prep_wht     <<<112, 256, 0, stream>>>(wc, wr, wht);
    rpn_screen_mfma  <<<dim3(128, 4), 512, 0, stream>>>(xT, wT, bb, wht, logits32);
    // xT/wT now dead: build rescue inputs over them
    rpn_prep_w       <<<dim3(144, 8), 256, 0, stream>>>(wb, wt);
    rpn_screen_decode<<<576, 256, 0, stream>>>(logits32, bc, br, keys32, hist1);
    rpn_select1      <<<1, 256, 0, stream>>>(hist1, meta);
    rpn_hist2        <<<576, 256, 0, stream>>>(keys32, meta, hist2);
    rpn_select2      <<<1, 256, 0, stream>>>(hist2, meta);
    rpn_compact      <<<576, 256, 0, stream>>>(keys32, meta, sel_idx, pxflag);
    rpn_px_compact   <<<64, 256, 0, stream>>>(pxflag, meta, pxlist, pxslot);
    rpn_rescue_gemm  <<<dim3(256, 8), 256, 0, stream>>>(x, wt, pxlist, meta, base64);
    rpn_rescue_heads <<<1024, 256, 0, stream>>>(base64, wht, bb, bc, br, meta, logits64);
    rpn_rescue_decode<<<16, 256, 0, stream>>>(logits64, sel_idx, pxslot, meta,
                                              boxes_d, sc32, sel);
    rpn_sort         <<<1, 1024, 0, stream>>>(sel, meta, boxes_d, sc32, out, bsel, vsel);
    rpn_nms_mask     <<<(N_PRE * NWORDS + 255) / 256, 256, 0, stream>>>(bsel, mask);
    rpn_nms_scan     <<<1, 64, 0, stream>>>(mask, vsel, keep, rank);
    rpn_finalize     <<<12, 256, 0, stream>>>(keep, rank, bsel, out);
}

// Round 20
// 1821.690 us; speedup vs baseline: 1.3509x; 1.3509x over previous
//
#include <hip/hip_runtime.h>
#include <cmath>

typedef unsigned long long u64;
typedef __attribute__((ext_vector_type(8))) short short8;
typedef __attribute__((ext_vector_type(4))) float f32x4;
typedef __attribute__((ext_vector_type(4))) double f64x4;

#define N_ANCH   147456      // 128*128*9
#define N_SCREEN 3600        // screen candidates (rank margin 600)
#define N_PRE    3000
#define N_POST   300
#define NWORDS   47          // ceil(3000/64)
#define SEL_CAP  4096

__device__ inline short f2bf(float f) {          // f32 -> bf16 RNE
    unsigned u = __float_as_uint(f);
    unsigned r = u + 0x7FFFu + ((u >> 16) & 1u);
    return (short)(r >> 16);
}

// ---------------- prep: x -> xT[h][w][c] bf16 ----------------
__global__ __launch_bounds__(256) void rpn_prep_xT(const float* __restrict__ x,
                                                   short* __restrict__ xT) {
    __shared__ short tile[32][258];
    const int h  = blockIdx.x;
    const int w0 = blockIdx.y * 32;
    const int c0 = blockIdx.z * 256;
    const int tid = threadIdx.x;
    const int wi = tid & 31, cs = tid >> 5;
    #pragma unroll
    for (int it = 0; it < 32; ++it) {
        int c = it * 8 + cs;
        float v = x[(size_t)(c0 + c) * 16384 + h * 128 + w0 + wi];
        tile[wi][c] = f2bf(v);
    }
    __syncthreads();
    #pragma unroll
    for (int it = 0; it < 32; ++it) {
        int i = tid + it * 256;
        int wj = i >> 8, c = i & 255;
        xT[((size_t)h * 128 + w0 + wj) * 1024 + c0 + c] = tile[wj][c];
    }
}

// ---------------- prep: wb -> wT[t][oc][c] bf16 ----------------
__global__ __launch_bounds__(256) void rpn_prep_wbf(const float* __restrict__ wb,
                                                    short* __restrict__ wT) {
    __shared__ float wtile[2304];
    const int oc = blockIdx.x;
    const int c0 = blockIdx.y * 256;
    const int tid = threadIdx.x;
    #pragma unroll
    for (int it = 0; it < 9; ++it) {
        int i = tid + it * 256;
        wtile[i] = wb[(size_t)oc * 9216 + c0 * 9 + i];
    }
    __syncthreads();
    #pragma unroll
    for (int it = 0; it < 9; ++it) {
        int i = tid + it * 256;
        int t = i >> 8, c = i & 255;
        wT[((size_t)t * 512 + oc) * 1024 + c0 + c] = f2bf(wtile[c * 9 + t]);
    }
}

// ---------------- prep: wb -> wt[c*9+t][oc] f32 (for f64 rescue; runs AFTER screen) ----
__global__ __launch_bounds__(256) void rpn_prep_w(const float* __restrict__ wb,
                                                  float* __restrict__ wt) {
    __shared__ float tile[64][65];
    const int bx = blockIdx.x;           // rem tile: 144 * 64 = 9216
    const int by = blockIdx.y;           // oc  tile:   8 * 64 = 512
    const int tid = threadIdx.x;
    #pragma unroll
    for (int it = 0; it < 16; ++it) {
        int i = tid + it * 256;
        int r = i >> 6, c = i & 63;
        tile[r][c] = wb[(size_t)(by * 64 + r) * 9216 + bx * 64 + c];
    }
    __syncthreads();
    #pragma unroll
    for (int it = 0; it < 16; ++it) {
        int i = tid + it * 256;
        int r = i >> 6, c = i & 63;
        wt[(size_t)(bx * 64 + r) * 512 + by * 64 + c] = tile[c][r];
    }
}

__global__ void rpn_prep_wht(const float* __restrict__ wc, const float* __restrict__ wr,
                             float* __restrict__ wht) {
    int i = blockIdx.x * 256 + threadIdx.x;           // < 512*56
    if (i >= 512 * 56) return;
    int c = i / 56, k = i - c * 56;
    float v = 0.f;
    if (k < 18)       v = wc[k * 512 + c];
    else if (k < 54)  v = wr[(k - 18) * 512 + c];
    wht[i] = v;
}

// ---------------- bf16 MFMA SCREEN v4: 512 thr, LDS-reduced epilogue ----------------
// Block 512 thr = 8 waves. Wave: 32 oc x 64 px (wocB=(wave&3)*32, wpx=(wave>>2)*64).
// Grid (128 rows, 4 ocT of 128 oc). Epilogue reduces the 4 oc-groups in LDS and
// issues ONE atomic per (px,q) cell per block (4x fewer atomics than v3).
#define STAGE_LOADM(WREG, XREG, CN)                                            \
    {                                                                          \
        _Pragma("unroll")                                                      \
        for (int it = 0; it < 9; ++it)                                         \
            WREG[it] = *(const short8*)&wT[wgo[it] + (CN)];                    \
        _Pragma("unroll")                                                      \
        for (int it = 0; it < 4; ++it)                                         \
            XREG[it] = (xgo[it] >= 0) ? *(const short8*)&xT[xgo[it] + (CN)]    \
                                      : zer;                                   \
    }
#define STAGE_WRITEM(WREG, XREG)                                               \
    {                                                                          \
        _Pragma("unroll")                                                      \
        for (int it = 0; it < 9; ++it) *(short8*)&wsm[wlo[it]] = WREG[it];     \
        _Pragma("unroll")                                                      \
        for (int it = 0; it < 4; ++it)                                         \
            if (xlo[it] >= 0) *(short8*)&xsm[xlo[it]] = XREG[it];              \
    }
#define MFMA_CHUNKM()                                                          \
    {                                                                          \
        _Pragma("unroll")                                                      \
        for (int t = 0; t < 9; ++t) {                                          \
            int kh = t / 3, kw = t - kh * 3;                                   \
            int ra0 = t * 128 + wocB + l15;                                    \
            int ra1 = ra0 + 16;                                                \
            short8 a0 = *(const short8*)&wsm[ra0 * 32 + ((lg ^ ((ra0 >> 1) & 3)) << 3)]; \
            short8 a1 = *(const short8*)&wsm[ra1 * 32 + ((lg ^ ((ra1 >> 1) & 3)) << 3)]; \
            _Pragma("unroll")                                                  \
            for (int nf = 0; nf < 4; ++nf) {                                   \
                int rb = kh * 130 + wpx + nf * 16 + l15 + kw;                  \
                short8 b = *(const short8*)&xsm[rb * 32 + ((lg ^ ((rb >> 1) & 3)) << 3)]; \
                acc[0][nf] = __builtin_amdgcn_mfma_f32_16x16x32_bf16(a0, b, acc[0][nf], 0, 0, 0); \
                acc[1][nf] = __builtin_amdgcn_mfma_f32_16x16x32_bf16(a1, b, acc[1][nf], 0, 0, 0); \
            }                                                                  \
        }                                                                      \
    }

__global__ __launch_bounds__(512, 2) void rpn_screen_mfma(
    const short* __restrict__ xT, const short* __restrict__ wT,
    const float* __restrict__ bb, const float* __restrict__ wht_,
    float* __restrict__ logits) {
    const int row = blockIdx.x;
    const int ocB = blockIdx.y * 128;
    const int tid = threadIdx.x;
    const int wave = tid >> 6, lane = tid & 63;
    const int l15 = lane & 15, lg = lane >> 4;
    const int wocB = (wave & 3) * 32;
    const int wpx  = (wave >> 2) * 64;
    __shared__ __attribute__((aligned(16))) short wsm[1152 * 32];  // 73,728B
    __shared__ __attribute__((aligned(16))) short xsm[390 * 32];   // 24,960B

    // ---- hoisted staging geometry (chunk-invariant; add c0 per chunk) ----
    size_t wgo[9];  int wlo[9];
    #pragma unroll
    for (int it = 0; it < 9; ++it) {
        int i = tid + it * 512;          // 0..4607
        int r = i >> 2, s = i & 3;       // r < 1152
        int t = r >> 7, ocl = r & 127;
        wgo[it] = ((size_t)t * 512 + ocB + ocl) * 1024 + s * 8;
        wlo[it] = r * 32 + ((s ^ ((r >> 1) & 3)) << 3);
    }
    long xgo[4]; int xlo[4];
    #pragma unroll
    for (int it = 0; it < 4; ++it) {
        int i = tid + it * 512;
        xlo[it] = -1; xgo[it] = -1;
        if (i < 1560) {
            int r = i >> 2, s = i & 3;
            int r3 = r / 130, col = r - r3 * 130;
            int h = row - 1 + r3, wc = col - 1;
            xlo[it] = r * 32 + ((s ^ ((r >> 1) & 3)) << 3);
            xgo[it] = (h >= 0 && h < 128 && wc >= 0 && wc < 128)
                      ? (long)(((size_t)h * 128 + wc) * 1024 + s * 8) : -1;
        }
    }

    f32x4 acc[2][4];
    #pragma unroll
    for (int mi = 0; mi < 2; ++mi)
        #pragma unroll
        for (int nf = 0; nf < 4; ++nf)
            acc[mi][nf] = (f32x4){0.f, 0.f, 0.f, 0.f};

    short8 wregA[9], xregA[4], wregB[9], xregB[4];
    const short8 zer = {0, 0, 0, 0, 0, 0, 0, 0};

    STAGE_LOADM(wregA, xregA, 0);
    STAGE_LOADM(wregB, xregB, 32);

    for (int i2 = 0; i2 < 16; ++i2) {
        int cA = i2 * 64;
        __syncthreads();
        STAGE_WRITEM(wregA, xregA);
        __syncthreads();
        if (cA + 64 < 1024) STAGE_LOADM(wregA, xregA, cA + 64);
        MFMA_CHUNKM();
        __syncthreads();
        STAGE_WRITEM(wregB, xregB);
        __syncthreads();
        if (cA + 96 < 1024) STAGE_LOADM(wregB, xregB, cA + 96);
        MFMA_CHUNKM();
    }

    // epilogue: bias+relu, fold heads, LDS-reduce 4 oc-groups, 1 atomic/cell
    float r_[8][4];
    #pragma unroll
    for (int mi = 0; mi < 2; ++mi)
        #pragma unroll
        for (int rr = 0; rr < 4; ++rr) {
            int ocg = ocB + wocB + mi * 16 + lg * 4 + rr;
            float bv = bb[ocg];
            #pragma unroll
            for (int nf = 0; nf < 4; ++nf)
                r_[mi * 4 + rr][nf] = fmaxf(acc[mi][nf][rr] + bv, 0.f);
        }
    float* lred = (float*)wsm;           // [4 ocGroup][128 px][4 qq] = 8 KB
    const int pxc = tid >> 2, qqc = tid & 3;      // cell assignment for reduce pass
    for (int qc = 0; qc < 14; ++qc) {
        float wq[8][4];
        #pragma unroll
        for (int p = 0; p < 8; ++p) {
            int ocg = ocB + wocB + (p >> 2) * 16 + lg * 4 + (p & 3);
            float4 wv = *(const float4*)&wht_[(size_t)ocg * 56 + qc * 4];
            wq[p][0] = wv.x; wq[p][1] = wv.y; wq[p][2] = wv.z; wq[p][3] = wv.w;
        }
        __syncthreads();                 // lred free (prev qc reads / main-loop reads done)
        #pragma unroll
        for (int nf = 0; nf < 4; ++nf) {
            #pragma unroll
            for (int qq = 0; qq < 4; ++qq) {
                float s = 0.f;
                #pragma unroll
                for (int p = 0; p < 8; ++p) s = fmaf(r_[p][nf], wq[p][qq], s);
                s += __shfl_xor(s, 16);
                s += __shfl_xor(s, 32);          // sum over wave's 32 oc
                if (lg == 0)
                    lred[(((wave & 3) * 128) + wpx + nf * 16 + l15) * 4 + qq] = s;
            }
        }
        __syncthreads();
        float v = lred[(0 * 128 + pxc) * 4 + qqc] + lred[(1 * 128 + pxc) * 4 + qqc]
                + lred[(2 * 128 + pxc) * 4 + qqc] + lred[(3 * 128 + pxc) * 4 + qqc];
        atomicAdd(&logits[(size_t)(row * 128 + pxc) * 56 + qc * 4 + qqc], v);
    }
}

// ---------------- f32 screen decode + hist1 (fused) ----------------
__global__ void rpn_screen_decode(
    const float* __restrict__ logits, const float* __restrict__ bc,
    const float* __restrict__ br, unsigned* __restrict__ keys32,
    unsigned* __restrict__ hist1) {
    int aidx = blockIdx.x * 256 + threadIdx.x;
    if (aidx >= N_ANCH) return;
    int px = aidx / 9, a = aidx - px * 9;
    int wix = px & 127, hix = px >> 7;
    float Xf = (float)(wix * 16), Yf = (float)(hix * 16);
    int ri = a / 3, si = a - ri * 3;
    double rr  = (ri == 0) ? 0.5 : ((ri == 1) ? 1.0 : 2.0);
    double scl = (si == 0) ? 8.0 : ((si == 1) ? 16.0 : 32.0);
    double wA = 16.0 * scl * sqrt(1.0 / rr);
    double hA = 16.0 * scl * sqrt(rr);
    float c0 = (float)(-0.5 * wA), c1 = (float)(-0.5 * hA);
    float c2 = (float)( 0.5 * wA), c3 = (float)( 0.5 * hA);
    float ax1 = Xf + c0, ay1 = Yf + c1, ax2 = Xf + c2, ay2 = Yf + c3;
    float aw = ax2 - ax1, ah = ay2 - ay1;
    float acx = ax1 + 0.5f * aw, acy = ay1 + 0.5f * ah;
    const float* L = &logits[(size_t)px * 56];
    float l0 = L[2 * a]     + bc[2 * a];
    float l1 = L[2 * a + 1] + bc[2 * a + 1];
    float dx = L[18 + 4 * a + 0] + br[4 * a + 0];
    float dy = L[18 + 4 * a + 1] + br[4 * a + 1];
    float dw = L[18 + 4 * a + 2] + br[4 * a + 2];
    float dh = L[18 + 4 * a + 3] + br[4 * a + 3];
    float cx = dx * aw + acx, cy = dy * ah + acy;
    float bw = expf(dw) * aw, bh = expf(dh) * ah;
    float x1 = fminf(fmaxf(cx - 0.5f * bw, 0.f), 2048.f);
    float y1 = fminf(fmaxf(cy - 0.5f * bh, 0.f), 2048.f);
    float x2 = fminf(fmaxf(cx + 0.5f * bw, 0.f), 2048.f);
    float y2 = fminf(fmaxf(cy + 0.5f * bh, 0.f), 2048.f);
    // fuzzy validity: wide slack for bf16 screen error; exact test in f64 rescue
    bool valid = (x2 - x1 >= 12.0f) && (y2 - y1 >= 12.0f);
    float m = fmaxf(l0, l1);
    float e0 = expf(l0 - m), e1 = expf(l1 - m);
    float fg = e1 / (e0 + e1);
    float msk = valid ? fg : -INFINITY;
    unsigned kb = __float_as_uint(msk);
    kb = (kb & 0x80000000u) ? ~kb : (kb | 0x80000000u);
    keys32[aidx] = kb;
    atomicAdd(&hist1[kb >> 16], 1u);
}

// ---------------- top-N_SCREEN: two-level radix select on fp32 key ----------------
__global__ void rpn_select1(const unsigned* __restrict__ hist, unsigned* __restrict__ meta) {
    __shared__ unsigned seg[256];
    __shared__ unsigned suf[257];
    int t = threadIdx.x;
    unsigned s = 0;
    for (int j = 0; j < 256; ++j) s += hist[t * 256 + j];
    seg[t] = s;
    __syncthreads();
    if (t == 0) {
        unsigned run = 0; suf[256] = 0;
        for (int q = 255; q >= 0; --q) { run += seg[q]; suf[q] = run; }
    }
    __syncthreads();
    if (suf[t + 1] < N_SCREEN && suf[t] >= N_SCREEN) {
        unsigned cum = suf[t + 1];
        for (int b = t * 256 + 255; b >= t * 256; --b) {
            unsigned prev = cum;
            cum += hist[b];
            if (cum >= N_SCREEN) { meta[0] = (unsigned)b; meta[1] = prev; break; }
        }
    }
}

__global__ void rpn_hist2(const unsigned* __restrict__ keys, const unsigned* __restrict__ meta,
                          unsigned* __restrict__ hist2) {
    int i = blockIdx.x * 256 + threadIdx.x;
    if (i >= N_ANCH) return;
    unsigned B = meta[0];
    unsigned k = keys[i];
    if ((k >> 16) == B) atomicAdd(&hist2[k & 0xFFFFu], 1u);
}

__global__ void rpn_select2(const unsigned* __restrict__ hist2, unsigned* __restrict__ meta) {
    __shared__ unsigned seg[256];
    __shared__ unsigned suf[257];
    int t = threadIdx.x;
    unsigned s = 0;
    for (int j = 0; j < 256; ++j) s += hist2[t * 256 + j];
    seg[t] = s;
    __syncthreads();
    if (t == 0) {
        unsigned run = 0; suf[256] = 0;
        for (int q = 255; q >= 0; --q) { run += seg[q]; suf[q] = run; }
    }
    __syncthreads();
    unsigned need = N_SCREEN - meta[1];          // >= 1 by construction
    if (suf[t + 1] < need && suf[t] >= need) {
        unsigned cum = suf[t + 1];
        for (int b = t * 256 + 255; b >= t * 256; --b) {
            cum += hist2[b];
            if (cum >= need) { meta[3] = (meta[0] << 16) | (unsigned)b; break; }
        }
    }
}

// compact + pixel-mark fused
__global__ void rpn_compact(const unsigned* __restrict__ keys, unsigned* meta,
                            int* __restrict__ sel_idx, unsigned* __restrict__ pxflag) {
    int i = blockIdx.x * 256 + threadIdx.x;
    if (i >= N_ANCH) return;
    if (keys[i] >= meta[3]) {
        unsigned pos = atomicAdd(&meta[4], 1u);
        if (pos < SEL_CAP) {
            sel_idx[pos] = i;
            pxflag[i / 9] = 1u;
        }
    }
}

__global__ void rpn_px_compact(const unsigned* __restrict__ pxflag, unsigned* meta,
                               int* __restrict__ pxlist, int* __restrict__ pxslot) {
    int px = blockIdx.x * 256 + threadIdx.x;
    if (px >= 16384) return;
    if (pxflag[px]) {
        int slot = (int)atomicAdd(&meta[5], 1u);
        pxlist[slot] = px;
        pxslot[px] = slot;
    }
}

// ---------------- f64 rescue GEMM v7b: f64 MFMA with SELF-CALIBRATING D layout ----------
// Grid (256 slot-tiles of 16, 8 ocT of 64). Block: 256 thr = 4 waves, wave = 16-oc group.
// Full K=9216 in-block -> direct stores, no atomics. K order: k = c*9 + tap (c asc).
__global__ __launch_bounds__(256) void rpn_rescue_gemm(
    const float* __restrict__ x, const float* __restrict__ wt,
    const int* __restrict__ pxlist, const unsigned* __restrict__ meta,
    double* __restrict__ base64) {
    int npx = (int)meta[5];
    int s0 = blockIdx.x * 16;
    if (s0 >= npx) return;
    const int tid  = threadIdx.x;
    const int wave = tid >> 6, lane = tid & 63;
    const int l15 = lane & 15, lg = lane >> 4;
    const int ocg = blockIdx.y * 64 + wave * 16;     // wave's 16-oc group base
    __shared__ double xs[144][17];                   // [kk][slot], 19,584 B

    // ---- layout probes ----
    f64x4 p1 = (f64x4){0.0, 0.0, 0.0, 0.0};
    f64x4 p2 = (f64x4){0.0, 0.0, 0.0, 0.0};
    p1 = __builtin_amdgcn_mfma_f64_16x16x4f64((double)l15, 1.0, p1, 0, 0, 0);
    p2 = __builtin_amdgcn_mfma_f64_16x16x4f64(1.0, (double)l15, p2, 0, 0, 0);
    int srow[4], scol[4];
    #pragma unroll
    for (int r = 0; r < 4; ++r) {
        srow[r] = (int)(p1[r] * 0.25 + 0.5);     // intended slot feeding this output
        scol[r] = (int)(p2[r] * 0.25 + 0.5);     // intended oc-offset feeding this output
    }

    // hoisted gather geometry: task j = tid + it*256 (exactly 2304 = 144*16 tasks)
    int sp_off[9];      // yy*128+xx or -1 (OOB)
    int ch_of[9];       // cLocal (0..15)
    #pragma unroll
    for (int it = 0; it < 9; ++it) {
        int j = tid + it * 256;
        int kk = j >> 4, slot = j & 15;
        int cl = kk / 9, tap = kk - cl * 9;
        int sg = s0 + slot;
        int pv = pxlist[(sg < npx) ? sg : s0];
        int yy = (pv >> 7) + tap / 3 - 1;
        int xx = (pv & 127) + tap % 3 - 1;
        sp_off[it] = (yy >= 0 && yy < 128 && xx >= 0 && xx < 128) ? (yy * 128 + xx) : -1;
        ch_of[it] = cl;
    }

    f64x4 acc = (f64x4){0.0, 0.0, 0.0, 0.0};
    float xreg[9];

    // prologue: gather channels 0..15
    #pragma unroll
    for (int it = 0; it < 9; ++it)
        xreg[it] = (sp_off[it] >= 0) ? x[(size_t)ch_of[it] * 16384 + sp_off[it]] : 0.f;

    const size_t wlane = (size_t)(ocg + l15) + (size_t)lg * 512;
    for (int c0 = 0; c0 < 1024; c0 += 16) {
        __syncthreads();
        #pragma unroll
        for (int it = 0; it < 9; ++it) {
            int j = tid + it * 256;
            xs[j >> 4][j & 15] = (double)xreg[it];
        }
        __syncthreads();
        if (c0 + 16 < 1024) {
            #pragma unroll
            for (int it = 0; it < 9; ++it)
                xreg[it] = (sp_off[it] >= 0)
                           ? x[(size_t)(c0 + 16 + ch_of[it]) * 16384 + sp_off[it]] : 0.f;
        }
        // 36 k-steps of K=4 over this round's 144 (c,tap) values.
        const size_t wbase = (size_t)c0 * 4608 + wlane;
        #pragma unroll
        for (int ks = 0; ks < 36; ++ks) {
            double a = xs[ks * 4 + lg][l15];
            double b = (double)wt[wbase + (size_t)ks * 2048];
            acc = __builtin_amdgcn_mfma_f64_16x16x4f64(a, b, acc, 0, 0, 0);
        }
    }
    #pragma unroll
    for (int r = 0; r < 4; ++r) {
        int slot = s0 + srow[r];
        if (slot < npx)
            base64[(size_t)slot * 512 + ocg + scol[r]] = acc[r];
    }
}

// ---------------- f64 rescue heads: LDS-staged base, bias+relu at staging ----------------
__global__ __launch_bounds__(256) void rpn_rescue_heads(
    const double* __restrict__ base64, const float* __restrict__ wht,
    const float* __restrict__ bb, const float* __restrict__ bc,
    const float* __restrict__ br, const unsigned* __restrict__ meta,
    double* __restrict__ logits64) {
    int npx = (int)meta[5]; if (npx > SEL_CAP) npx = SEL_CAP;
    int slot0 = blockIdx.x * 4;
    if (slot0 >= npx) return;
    const int tid = threadIdx.x;
    __shared__ double bs[4][514];        // padded: rows 4 banks apart
    for (int i = tid; i < 4 * 512; i += 256) {
        int s = i >> 9, c = i & 511;
        int slt = slot0 + s;
        double v = (slt < npx) ? base64[(size_t)slt * 512 + c] : 0.0;
        double r = v + (double)bb[c];
        bs[s][c] = (r > 0.0) ? r : 0.0;  // conv bias + relu applied once here
    }
    __syncthreads();
    if (tid < 224) {
        int s = tid / 56, q = tid - s * 56;
        int slt = slot0 + s;
        if (slt < npx) {
            double acc = (q < 18) ? (double)bc[q] : ((q < 54) ? (double)br[q - 18] : 0.0);
            const double* b = bs[s];
            #pragma unroll 8
            for (int c = 0; c < 512; ++c)
                acc = fma(b[c], (double)wht[c * 56 + q], acc);
            logits64[(size_t)slt * 56 + q] = acc;
        }
    }
}

// ---------------- f64 rescue decode: exact boxes/scores/keys ----------------
__global__ void rpn_rescue_decode(
    const double* __restrict__ logits64, const int* __restrict__ sel_idx,
    const int* __restrict__ pxslot, const unsigned* __restrict__ meta,
    double* __restrict__ boxes_d, float* __restrict__ sc32, u64* __restrict__ sel) {
    int i = blockIdx.x * 256 + threadIdx.x;
    unsigned M = meta[4]; if (M > SEL_CAP) M = SEL_CAP;
    if (i >= (int)M) return;
    int aidx = sel_idx[i];
    int px = aidx / 9, a = aidx - px * 9;
    int slot = pxslot[px];
    int wix = px & 127, hix = px >> 7;
    float Xf = (float)(wix * 16), Yf = (float)(hix * 16);
    int ri = a / 3, si = a - ri * 3;
    double rr  = (ri == 0) ? 0.5 : ((ri == 1) ? 1.0 : 2.0);
    double scl = (si == 0) ? 8.0 : ((si == 1) ? 16.0 : 32.0);
    double wA = 16.0 * scl * sqrt(1.0 / rr);
    double hA = 16.0 * scl * sqrt(rr);
    // anchors are float32 in the reference (np.asarray(ba, np.float32))
    float c0 = (float)(-0.5 * wA), c1 = (float)(-0.5 * hA);
    float c2 = (float)( 0.5 * wA), c3 = (float)( 0.5 * hA);
    float ax1 = Xf + c0, ay1 = Yf + c1, ax2 = Xf + c2, ay2 = Yf + c3;
    float awf = ax2 - ax1, ahf = ay2 - ay1;
    float acxf = ax1 + 0.5f * awf, acyf = ay1 + 0.5f * ahf;
    double aw = (double)awf, ah = (double)ahf;
    double acx = (double)acxf, acy = (double)acyf;
    const double* L = &logits64[(size_t)slot * 56];
    double l0 = L[2 * a], l1 = L[2 * a + 1];
    double dx = L[18 + 4 * a + 0], dy = L[18 + 4 * a + 1];
    double dw = L[18 + 4 * a + 2], dh = L[18 + 4 * a + 3];
    double cx = dx * aw + acx, cy = dy * ah + acy;
    double bw = exp(dw) * aw, bh = exp(dh) * ah;
    double x1 = fmin(fmax(cx - 0.5 * bw, 0.0), 2048.0);
    double y1 = fmin(fmax(cy - 0.5 * bh, 0.0), 2048.0);
    double x2 = fmin(fmax(cx + 0.5 * bw, 0.0), 2048.0);
    double y2 = fmin(fmax(cy + 0.5 * bh, 0.0), 2048.0);
    bool valid = (x2 - x1 >= 16.0) && (y2 - y1 >= 16.0);
    double m = fmax(l0, l1);
    double e0 = exp(l0 - m), e1 = exp(l1 - m);
    double fg = e1 / (e0 + e1);
    double msk = valid ? fg : -INFINITY;
    double* bd = &boxes_d[(size_t)aidx * 4];
    bd[0] = x1; bd[1] = y1; bd[2] = x2; bd[3] = y2;
    sc32[aidx] = (float)msk;
    long long ll = __double_as_longlong(msk);
    u64 u = (ll < 0) ? ~(u64)ll : ((u64)ll | 0x8000000000000000ull);
    sel[i] = (u & 0xFFFFFFFFFFFC0000ull) | (u64)(0x3FFFFu - (unsigned)aidx);
}

// ---------------- exact sort of candidates, take top-3000 ----------------
__global__ __launch_bounds__(1024) void rpn_sort(
    const u64* __restrict__ sel, const unsigned* __restrict__ meta,
    const double* __restrict__ boxes_d, const float* __restrict__ sc32,
    float* __restrict__ out, double* __restrict__ bsel, unsigned* __restrict__ vsel) {
    __shared__ u64 ss[SEL_CAP];
    int tid = threadIdx.x;
    int M = (int)meta[4]; if (M > SEL_CAP) M = SEL_CAP;
    for (int i = tid; i < SEL_CAP; i += 1024) ss[i] = (i < M) ? sel[i] : 0ULL;
    __syncthreads();
    for (int k = 2; k <= SEL_CAP; k <<= 1) {
        for (int j = k >> 1; j > 0; j >>= 1) {
            for (int i = tid; i < SEL_CAP; i += 1024) {
                int l = i ^ j;
                if (l > i) {
                    u64 a = ss[i], b = ss[l];
                    bool desc = (i & k) == 0;
                    if ((a < b) == desc) { ss[i] = b; ss[l] = a; }
                }
            }
            __syncthreads();
        }
    }
    for (int r = tid; r < N_PRE; r += 1024) {
        u64 key = ss[r];
        unsigned idx = 0x3FFFFu - (unsigned)(key & 0x3FFFFull);
        out[N_POST * 4 + r] = sc32[idx];
        const double* bd = &boxes_d[(size_t)idx * 4];
        double* dst = &bsel[(size_t)r * 4];
        dst[0] = bd[0]; dst[1] = bd[1]; dst[2] = bd[2]; dst[3] = bd[3];
        vsel[r] = (key >> 63) ? 1u : 0u;
    }
}

// ---------------- NMS (fp64 IoU) ----------------
__global__ void rpn_nms_mask(const double* __restrict__ bsel, u64* __restrict__ mask) {
    int t = blockIdx.x * 256 + threadIdx.x;
    if (t >= N_PRE * NWORDS) return;
    int i = t / NWORDS, w = t - i * NWORDS;
    const double* bi = &bsel[(size_t)i * 4];
    double bix1 = bi[0], biy1 = bi[1], bix2 = bi[2], biy2 = bi[3];
    double ai = (bix2 - bix1 + 1.0) * (biy2 - biy1 + 1.0);
    u64 bits = 0ULL;
    int j0 = w * 64;
    for (int jj = 0; jj < 64; ++jj) {
        int j = j0 + jj;
        if (j >= N_PRE || j == i) continue;
        const double* bj = &bsel[(size_t)j * 4];
        double aj = (bj[2] - bj[0] + 1.0) * (bj[3] - bj[1] + 1.0);
        double xx1 = fmax(bix1, bj[0]), yy1 = fmax(biy1, bj[1]);
        double xx2 = fmin(bix2, bj[2]), yy2 = fmin(biy2, bj[3]);
        double iw = fmax(xx2 - xx1 + 1.0, 0.0), ih = fmax(yy2 - yy1 + 1.0, 0.0);
        double inter = iw * ih;
        double iou = inter / (ai + aj - inter);
        if (iou > 0.5) bits |= 1ULL << jj;
    }
    mask[(size_t)i * NWORDS + w] = bits;
}

__global__ __launch_bounds__(64) void rpn_nms_scan(
    const u64* __restrict__ mask, const unsigned* __restrict__ vsel,
    unsigned* __restrict__ keep, unsigned* __restrict__ rank) {
    int lane = threadIdx.x;
    u64 remv = 0ULL;
    int kc = 0;
    u64 pre[8];
    unsigned vpre[8];
    #pragma unroll
    for (int q = 0; q < 8; ++q) {
        pre[q]  = (lane < NWORDS) ? mask[(size_t)q * NWORDS + lane] : 0ULL;
        vpre[q] = vsel[q];
    }
    for (int i0 = 0; i0 < N_PRE; i0 += 8) {
        u64 nxt[8];
        unsigned vnxt[8];
        #pragma unroll
        for (int q = 0; q < 8; ++q) {
            int r = i0 + 8 + q;
            nxt[q]  = (r < N_PRE && lane < NWORDS) ? mask[(size_t)r * NWORDS + lane] : 0ULL;
            vnxt[q] = (r < N_PRE) ? vsel[r] : 0u;
        }
        #pragma unroll
        for (int q = 0; q < 8; ++q) {
            int i = i0 + q;
            int word = i >> 6, bit = i & 63;
            u64 rw = __shfl(remv, word);
            bool sup = (rw >> bit) & 1ULL;
            bool kp = (vpre[q] != 0u) && !sup;
            if (kp) remv |= pre[q];
            if (lane == 0) { keep[i] = kp ? 1u : 0u; rank[i] = (unsigned)kc; }
            kc += kp ? 1 : 0;
        }
        #pragma unroll
        for (int q = 0; q < 8; ++q) { pre[q] = nxt[q]; vpre[q] = vnxt[q]; }
    }
}

__global__ void rpn_finalize(const unsigned* __restrict__ keep, const unsigned* __restrict__ rank,
                             const double* __restrict__ bsel, float* __restrict__ out) {
    int i = blockIdx.x * 256 + threadIdx.x;
    if (i < N_PRE && keep[i] && rank[i] < N_POST) {
        const double* b = &bsel[(size_t)i * 4];
        float4 v = make_float4((float)b[0], (float)b[1], (float)b[2], (float)b[3]);
        ((float4*)out)[rank[i]] = v;
    }
}

// ---------------- launch ----------------
extern "C" void kernel_launch(void* const* d_in, const int* in_sizes, int n_in,
                              void* d_out, int out_size, void* d_ws, size_t ws_size,
                              hipStream_t stream) {
    const float* x   = (const float*)d_in[0];
    const float* wb  = (const float*)d_in[1];
    const float* bb  = (const float*)d_in[2];
    const float* wc  = (const float*)d_in[3];
    const float* bc  = (const float*)d_in[4];
    const float* wr  = (const float*)d_in[5];
    const float* br  = (const float*)d_in[6];
    float* out = (float*)d_out;

    char* ws = (char*)d_ws;
    // Layout with overlays (total 56,490,752 B <= 57 MB proven-safe).
    // Phase 1 (prep+screen): xT@0 (33.5MB), wT@33.5MB (9.4MB) live.
    // Phase 2 (post-screen): wt@0 (18.9MB) and base64@18,874,368 (16.8MB)
    //   overlay the then-dead xT/wT regions.
    short*    xT       = (short*)(ws);                        // 33,554,432 (phase 1)
    float*    wt       = (float*)(ws);                        // 18,874,368 (phase 2)
    double*   base64   = (double*)(ws + 18874368);            // 16,777,216 (phase 2)
    short*    wT       = (short*)(ws + 33554432);             //  9,437,184 (phase 1)
    float*    logits32 = (float*)(ws + 42991616);             //  3,670,016
    float*    wht      = (float*)(ws + 46661632);             //    114,688
    double*   logits64 = (double*)(ws + 46776320);            //  1,835,008
    double*   boxes_d  = (double*)(ws + 48611328);            //  4,718,592
    float*    sc32     = (float*)(ws + 53329920);             //    589,824
    unsigned* keys32   = (unsigned*)(ws + 53919744);          //    589,824
    unsigned* hist1    = (unsigned*)(ws + 54509568);          //    262,144
    unsigned* hist2    = (unsigned*)(ws + 54771712);          //    262,144
    unsigned* meta     = (unsigned*)(ws + 55033856);          //        256
    int*      sel_idx  = (int*)(ws + 55034112);               //     16,384
    u64*      sel      = (u64*)(ws + 55050496);               //     32,768
    unsigned* pxflag   = (unsigned*)(ws + 55083264);          //     65,536
    int*      pxlist   = (int*)(ws + 55148800);               //     16,384
    int*      pxslot   = (int*)(ws + 55165184);               //     65,536
    double*   bsel     = (double*)(ws + 55230720);            //     96,000
    unsigned* vsel     = (unsigned*)(ws + 55326720);          //     12,032
    u64*      mask     = (u64*)(ws + 55338752);               //  1,128,000
    unsigned* keep     = (unsigned*)(ws + 56466752);          //     12,000
    unsigned* rank     = (unsigned*)(ws + 56478752);          //     12,000

    hipMemsetAsync(logits32, 0, 3670016, stream);
    hipMemsetAsync(hist1, 0, 262144 * 2 + 256, stream);       // hist1+hist2+meta
    hipMemsetAsync(pxflag, 0, 65536, stream);
    hipMemsetAsync(d_out, 0, N_POST * 4 * sizeof(float), stream);

    rpn_prep_xT      <<<dim3(128, 4, 4), 256, 0, stream>>>(x, xT);
    rpn_prep_wbf     <<<dim3(512, 4), 256, 0, stream>>>(wb, wT);
    rpn_prep_wht     <<<112, 256, 0, stream>>>(wc, wr, wht);
    rpn_screen_mfma  <<<dim3(128, 4), 512, 0, stream>>>(xT, wT, bb, wht, logits32);
    // xT/wT now dead: build rescue inputs over them
    rpn_prep_w       <<<dim3(144, 8), 256, 0, stream>>>(wb, wt);
    rpn_screen_decode<<<576, 256, 0, stream>>>(logits32, bc, br, keys32, hist1);
    rpn_select1      <<<1, 256, 0, stream>>>(hist1, meta);
    rpn_hist2        <<<576, 256, 0, stream>>>(keys32, meta, hist2);
    rpn_select2      <<<1, 256, 0, stream>>>(hist2, meta);
    rpn_compact      <<<576, 256, 0, stream>>>(keys32, meta, sel_idx, pxflag);
    rpn_px_compact   <<<64, 256, 0, stream>>>(pxflag, meta, pxlist, pxslot);
    rpn_rescue_gemm  <<<dim3(256, 8), 256, 0, stream>>>(x, wt, pxlist, meta, base64);
    rpn_rescue_heads <<<1024, 256, 0, stream>>>(base64, wht, bb, bc, br, meta, logits64);
    rpn_rescue_decode<<<16, 256, 0, stream>>>(logits64, sel_idx, pxslot, meta,
                                              boxes_d, sc32, sel);
    rpn_sort         <<<1, 1024, 0, stream>>>(sel, meta, boxes_d, sc32, out, bsel, vsel);
    rpn_nms_mask     <<<(N_PRE * NWORDS + 255) / 256, 256, 0, stream>>>(bsel, mask);
    rpn_nms_scan     <<<1, 64, 0, stream>>>(mask, vsel, keep, rank);
    rpn_finalize     <<<12, 256, 0, stream>>>(keep, rank, bsel, out);
}